// Round 16
// baseline (81.182 us; speedup 1.0000x reference)
//
#include <hip/hip_runtime.h>
#include <math.h>

#define BB 8
#define HH 128
#define WW 128
#define HW (HH*WW)
#define EPSV 1e-5f

typedef __attribute__((ext_vector_type(8))) _Float16 f16x8;
typedef __attribute__((ext_vector_type(4))) _Float16 f16x4;
typedef __attribute__((ext_vector_type(4))) float f32x4;

__device__ __forceinline__ short f2h(float f) {
    _Float16 h = (_Float16)f;
    return __builtin_bit_cast(short, h);
}
__device__ __forceinline__ f32x4 mfma_f16(f16x8 a, f16x8 b, f32x4 c) {
    return __builtin_amdgcn_mfma_f32_16x16x32_f16(a, b, c, 0, 0, 0);
}

// ---- prep: transpose x NCHW f32 -> NHWC fp16, + weight pack, + sums_p zero ----
__global__ __launch_bounds__(256) void prep_kernel(
    const float* __restrict__ x, short* __restrict__ xt,
    const float* __restrict__ w_dcn, const float* __restrict__ w_off,
    const float* __restrict__ w_mask,
    short* __restrict__ wtf_dcn, short* __restrict__ wtf_off,
    float* __restrict__ sums_p)
{
    __shared__ short tl[4096];
    const int t = threadIdx.x;
    const int blk = blockIdx.x;         // 2048 = 8b * 128h * 2wtiles

    if (blk < 216) {                    // folded-in weight pack
        int i = blk * 256 + t;
        if (i < 36864) {                // w_dcn: [(ks*4+nf)*64+lane]*8+e
            int e = i & 7, lane = (i >> 3) & 63, nf = (i >> 9) & 3, ks = i >> 11;
            int tt = ks * 32 + ((lane >> 4) << 3) + e;
            int o = (nf << 4) + (lane & 15);
            int k = tt >> 6, c = tt & 63;
            wtf_dcn[i] = f2h(w_dcn[(o * 64 + c) * 9 + k]);
        } else {                        // w_off/w_mask: [(ks*2+nf)*64+lane]*8+e
            int j = i - 36864;
            int e = j & 7, lane = (j >> 3) & 63, nf = (j >> 9) & 1, ks = j >> 10;
            int tt = ks * 32 + ((lane >> 4) << 3) + e;
            int oc = (nf << 4) + (lane & 15);
            int k = tt >> 6, c = tt & 63;
            float v = 0.f;
            if (oc < 18) v = w_off[(oc * 64 + c) * 9 + k];
            else if (oc < 27) v = w_mask[((oc - 18) * 64 + c) * 9 + k];
            wtf_off[j] = f2h(v);
        }
    } else if (blk == 1000) {           // zero BN partials (16 floats/thread)
#pragma unroll
        for (int i = 0; i < 16; ++i) sums_p[t + 256 * i] = 0.f;
    }

    const int b = blk >> 8, rem = blk & 255, h = rem >> 1, wb = (rem & 1) << 6;
    const int w4 = t & 15, ci = t >> 4;
#pragma unroll
    for (int i = 0; i < 4; ++i) {
        int c = i * 16 + ci;
        f32x4 v = *(const f32x4*)(x + (((b * 64 + c) * 128 + h) * 128) + wb + w4 * 4);
#pragma unroll
        for (int j = 0; j < 4; ++j) {
            int w = w4 * 4 + j;
            tl[w * 64 + (c ^ ((w & 7) << 3))] = f2h(v[j]);
        }
    }
    __syncthreads();
    const int p = t >> 2, q = t & 3;
    f16x8 a = *(const f16x8*)&tl[p * 64 + ((q * 16) ^ ((p & 7) << 3))];
    f16x8 bv = *(const f16x8*)&tl[p * 64 + ((q * 16 + 8) ^ ((p & 7) << 3))];
    short* dst = xt + ((((b << 7) | h) << 7) | (wb + p)) * 64 + q * 16;
    *(f16x8*)dst = a;
    *(f16x8*)(dst + 8) = bv;
}

// ---------------- fused conv: r9 structure + phase-B weights preloaded in registers ----------------
__global__ __launch_bounds__(256, 3) void fused_conv(
    const short* __restrict__ xt,
    const short* __restrict__ wtf_off, const short* __restrict__ wtf_dcn,
    const float* __restrict__ b_off, const float* __restrict__ b_mask,
    const float* __restrict__ b_dcn,
    _Float16* __restrict__ preh, float* __restrict__ sums_p)
{
    __shared__ __align__(16) short alds[2][4096];               // 16 KB double-buffered A-tile
    __shared__ float offy[9][66], offxl[9][66], offmm[9][66];   // padded (conflict-free)
    __shared__ float blkstats[2][64];

    const int tid = threadIdx.x;
    const int bid = blockIdx.x;
    if (tid < 128) blkstats[tid >> 6][tid & 63] = 0.f;

    const int tile = (bid & 7) * 256 + (bid >> 3);  // XCD-bijective, 2048 % 8 == 0
    const int pbase = tile << 6;
    const int b = pbase / HW;
    const int rembase = pbase % HW;                 // 64-px strip (one h row)
    const int hh0 = rembase >> 7;
    const int wb0 = rembase & 127;
    const int p = tid >> 2, q = tid & 3;            // staging role: pixel p, ch-quad q
    const int wp0 = wb0 + p;
    const int lane = tid & 63, wv = tid >> 6;
    const short* xb = xt + ((size_t)b << 20);

    const int ws0 = p * 64 + ((q * 16) ^ ((p & 7) << 3));
    const int ws1 = p * 64 + ((q * 16 + 8) ^ ((p & 7) << 3));

    // ================= Phase A: offset/mask conv (N=32) =================
    const int nfw = wv & 1, mh = wv >> 1;
    f16x8 s0v, s1v;
    auto issueND = [&](int k) {
        int yy = hh0 + (k / 3) - 1;
        int xx = wp0 + (k % 3) - 1;
        bool ok = (yy >= 0) && (yy < HH) && (xx >= 0) && (xx < WW);
        const short* src = xb + (((((yy & 127) << 7) | (xx & 127))) << 6) + q * 16;
        f16x8 z = {};
        s0v = ok ? *(const f16x8*)src : z;
        s1v = ok ? *(const f16x8*)(src + 8) : z;
    };
    auto writeND = [&](int buf) {
        *(f16x8*)&alds[buf][ws0] = s0v;
        *(f16x8*)&alds[buf][ws1] = s1v;
    };

    f32x4 acc2[2];
    acc2[0] = (f32x4){0.f, 0.f, 0.f, 0.f};
    acc2[1] = acc2[0];

    issueND(0);
    writeND(0);
    __syncthreads();
    int s = 0;
#pragma unroll 1
    for (int k = 0; k < 9; ++k) {
        if (k < 8) issueND(k + 1);                  // next-k loads fly under MFMA
        const short* bw = wtf_off + (4 * k + nfw) * 512;
        f16x8 b0 = *(const f16x8*)(bw + lane * 8);
        f16x8 b1 = *(const f16x8*)(bw + 1024 + lane * 8);   // ks=2k+1, same nfw
        __builtin_amdgcn_s_setprio(1);
#pragma unroll
        for (int kh = 0; kh < 2; ++kh) {
            f16x8 bb = kh ? b1 : b0;
#pragma unroll
            for (int i = 0; i < 2; ++i) {
                int px = (mh * 2 + i) * 16 + (lane & 15);
                int sidx = px * 64 + ((kh * 32 + ((lane >> 4) << 3)) ^ ((px & 7) << 3));
                f16x8 af = *(const f16x8*)&alds[s][sidx];
                acc2[i] = mfma_f16(af, bb, acc2[i]);
            }
        }
        __builtin_amdgcn_s_setprio(0);
        if (k < 8) writeND(s ^ 1);                  // other buffer: no hazard with reads
        __syncthreads();
        s ^= 1;
    }
    {   // epilogue A: offsets + sigmoid(mask) -> LDS (wave=(nfw,mh) layout)
        const int rq = lane >> 4;
        const int oc = nfw * 16 + (lane & 15);
#pragma unroll
        for (int i = 0; i < 2; ++i) {
#pragma unroll
            for (int j = 0; j < 4; ++j) {
                int px = (mh * 2 + i) * 16 + rq * 4 + j;
                float v = acc2[i][j];
                if (oc < 18) {
                    v += b_off[oc];
                    if (oc & 1) offxl[oc >> 1][px] = v; else offy[oc >> 1][px] = v;
                } else if (oc < 27) {
                    v += b_mask[oc - 18];
                    offmm[oc - 18][px] = 1.f / (1.f + __expf(-v));
                }
            }
        }
    }
    __syncthreads();

    // ================= Phase B: deformable conv (N=64), weights in registers =================
    const int nf = wv;                              // wave's 16-col N-fragment
    f32x4 acc[4];
#pragma unroll
    for (int i = 0; i < 4; ++i) acc[i] = (f32x4){0.f, 0.f, 0.f, 0.f};

    // preload ALL 18 B-fragments (loop-invariant addresses -> hoisted, stay in VGPRs)
    f16x8 wr0[9], wr1[9];
#pragma unroll
    for (int k = 0; k < 9; ++k) {
        const short* bw = wtf_dcn + (((8 * k) + nf) * 64 + lane) * 8;
        wr0[k] = *(const f16x8*)bw;
        wr1[k] = *(const f16x8*)(bw + 2048);
    }

    f16x8 c00a, c00b, c01a, c01b, c10a, c10b, c11a, c11b;
    _Float16 h00, h01, h10, h11;
    auto bilin = [&](int k) {
        float dyv = offy[k][p], dxv = offxl[k][p], mv = offmm[k][p];
        float py  = (float)(hh0 + (k / 3) - 1) + dyv;
        float pxf = (float)(wp0 + (k % 3) - 1) + dxv;
        float y0f = floorf(py), x0f = floorf(pxf);
        float ly = py - y0f, lx = pxf - x0f;
        int y0 = (int)y0f, x0 = (int)x0f;
        int y1 = y0 + 1, x1 = x0 + 1;
        float fy0 = (y0 >= 0 && y0 < HH) ? 1.f : 0.f;
        float fy1 = (y1 >= 0 && y1 < HH) ? 1.f : 0.f;
        float fx0 = (x0 >= 0 && x0 < WW) ? 1.f : 0.f;
        float fx1 = (x1 >= 0 && x1 < WW) ? 1.f : 0.f;
        int yc0 = min(max(y0, 0), HH - 1), yc1 = min(max(y1, 0), HH - 1);
        int xc0 = min(max(x0, 0), WW - 1), xc1 = min(max(x1, 0), WW - 1);
        h00 = (_Float16)((1.f - ly) * (1.f - lx) * mv * fy0 * fx0);
        h01 = (_Float16)((1.f - ly) * lx * mv * fy0 * fx1);
        h10 = (_Float16)(ly * (1.f - lx) * mv * fy1 * fx0);
        h11 = (_Float16)(ly * lx * mv * fy1 * fx1);
        const short* s00 = xb + (((yc0 << 7) | xc0) << 6) + q * 16;
        const short* s01 = xb + (((yc0 << 7) | xc1) << 6) + q * 16;
        const short* s10 = xb + (((yc1 << 7) | xc0) << 6) + q * 16;
        const short* s11 = xb + (((yc1 << 7) | xc1) << 6) + q * 16;
        c00a = *(const f16x8*)s00; c00b = *(const f16x8*)(s00 + 8);
        c01a = *(const f16x8*)s01; c01b = *(const f16x8*)(s01 + 8);
        c10a = *(const f16x8*)s10; c10b = *(const f16x8*)(s10 + 8);
        c11a = *(const f16x8*)s11; c11b = *(const f16x8*)(s11 + 8);
    };
    auto writeB = [&](int buf) {     // packed-fp16 bilinear interp
        f16x8 va = c00a * h00 + c01a * h01 + c10a * h10 + c11a * h11;
        f16x8 vb = c00b * h00 + c01b * h01 + c10b * h10 + c11b * h11;
        *(f16x8*)&alds[buf][ws0] = va;
        *(f16x8*)&alds[buf][ws1] = vb;
    };

    bilin(0);
    writeB(0);
    __syncthreads();
#pragma unroll
    for (int k = 0; k < 9; ++k) {
        const int sb = k & 1;                       // compile-time buffer select
        if (k < 8) bilin(k + 1);                    // next-k corner loads under MFMA
        __builtin_amdgcn_s_setprio(1);
#pragma unroll
        for (int kh = 0; kh < 2; ++kh) {
            f16x8 bb = kh ? wr1[k] : wr0[k];
#pragma unroll
            for (int mb = 0; mb < 4; ++mb) {
                int px = mb * 16 + (lane & 15);
                int sidx = px * 64 + ((kh * 32 + ((lane >> 4) << 3)) ^ ((px & 7) << 3));
                f16x8 af = *(const f16x8*)&alds[sb][sidx];
                acc[mb] = mfma_f16(af, bb, acc[mb]);
            }
        }
        __builtin_amdgcn_s_setprio(0);
        if (k < 8) writeB(sb ^ 1);
        __syncthreads();
    }

    // epilogue B: o = wv*16 + (lane&15); pixel = mb*16 + rq*4 + j
    {
        const int lr = lane & 15, rq = lane >> 4;
        const int o = nf * 16 + lr;
        const float bo = b_dcn[o];
        _Float16* dstp = preh + (size_t)(b * 64 + o) * HW + rembase;
        float sv = 0.f, s2 = 0.f;
#pragma unroll
        for (int mb = 0; mb < 4; ++mb) {
            f16x4 hv;
#pragma unroll
            for (int j = 0; j < 4; ++j) {
                float v = acc[mb][j] + bo;
                hv[j] = (_Float16)v;
                sv += v; s2 += v * v;
            }
            *(f16x4*)(dstp + mb * 16 + rq * 4) = hv;
        }
        sv += __shfl_xor(sv, 16);  sv += __shfl_xor(sv, 32);
        s2 += __shfl_xor(s2, 16);  s2 += __shfl_xor(s2, 32);
        if (lane < 16) {
            atomicAdd(&blkstats[0][o], sv);
            atomicAdd(&blkstats[1][o], s2);
        }
    }
    __syncthreads();
    if (tid < 64) {
        int slot = bid & 31;
        atomicAdd(&sums_p[slot * 64 + tid], blkstats[0][tid]);           // [slot][ch] coalesced
        atomicAdd(&sums_p[2048 + slot * 64 + tid], blkstats[1][tid]);
    }
}

// ---------------- BN apply + fast Mish: mish(t) = t*(u²+2u)/(u²+2u+2), u=e^t ----------------
__global__ __launch_bounds__(256) void bn_mish(
    const _Float16* __restrict__ preh, const float* __restrict__ sums_p,
    const float* __restrict__ gamma, const float* __restrict__ beta,
    float* __restrict__ out)
{
    int vid = blockIdx.x * 256 + threadIdx.x;       // f16x8 chunk index
    int c = (vid >> 11) & 63;                       // uniform per block
    float sm = 0.f, sq = 0.f;
#pragma unroll
    for (int s = 0; s < 32; ++s) {                  // uniform scalar loads, L2-hot
        sm += sums_p[s * 64 + c];
        sq += sums_p[2048 + s * 64 + c];
    }
    const float invN = 1.f / (float)(BB * HW);
    float mean = sm * invN;
    float rstd = rsqrtf(sq * invN - mean * mean + EPSV);
    float g = gamma[c] * rstd;
    float be = beta[c] - mean * g;
    f16x8 v = ((const f16x8*)preh)[vid];
    float* dst = out + (size_t)vid * 8;
    f32x4 r0, r1;
#pragma unroll
    for (int j = 0; j < 8; ++j) {
        float t = (float)v[j] * g + be;
        float u = __expf(fminf(t, 20.f));
        float w = u * u + 2.f * u;
        float m = t * (w / (w + 2.f));
        if (j < 4) r0[j] = m; else r1[j - 4] = m;
    }
    *(f32x4*)dst = r0;
    *(f32x4*)(dst + 4) = r1;
}

extern "C" void kernel_launch(void* const* d_in, const int* in_sizes, int n_in,
                              void* d_out, int out_size, void* d_ws, size_t ws_size,
                              hipStream_t stream) {
    const float* x      = (const float*)d_in[0];
    const float* w_off  = (const float*)d_in[1];
    const float* b_off  = (const float*)d_in[2];
    const float* w_mask = (const float*)d_in[3];
    const float* b_mask = (const float*)d_in[4];
    const float* w_dcn  = (const float*)d_in[5];
    const float* b_dcn  = (const float*)d_in[6];
    const float* gamma  = (const float*)d_in[7];
    const float* beta   = (const float*)d_in[8];
    float* out = (float*)d_out;

    float* sums_p  = (float*)d_ws;                  // 4096 floats (2 x 32slot x 64ch)
    short* wtf_dcn = (short*)(sums_p + 4096);       // 36864 shorts
    short* wtf_off = wtf_dcn + 36864;               // 18432 shorts
    short* xt      = wtf_off + 18432;               // 8388608 shorts (NHWC fp16)
    _Float16* preh = (_Float16*)(xt + 8388608);     // 8388608 halfs

    prep_kernel<<<2048, 256, 0, stream>>>(x, xt, w_dcn, w_off, w_mask, wtf_dcn, wtf_off, sums_p);
    fused_conv<<<2048, 256, 0, stream>>>(xt, wtf_off, wtf_dcn, b_off, b_mask, b_dcn, preh, sums_p);
    bn_mish<<<4096, 256, 0, stream>>>(preh, sums_p, gamma, beta, out);
}

// Round 17
// 75.336 us; speedup vs baseline: 1.0776x; 1.0776x over previous
//
#include <hip/hip_runtime.h>
#include <math.h>

#define BB 8
#define HH 128
#define WW 128
#define HW (HH*WW)
#define EPSV 1e-5f

typedef __attribute__((ext_vector_type(8))) _Float16 f16x8;
typedef __attribute__((ext_vector_type(4))) _Float16 f16x4;
typedef __attribute__((ext_vector_type(4))) float f32x4;

__device__ __forceinline__ short f2h(float f) {
    _Float16 h = (_Float16)f;
    return __builtin_bit_cast(short, h);
}
__device__ __forceinline__ f32x4 mfma_f16(f16x8 a, f16x8 b, f32x4 c) {
    return __builtin_amdgcn_mfma_f32_16x16x32_f16(a, b, c, 0, 0, 0);
}

// ---- prep: transpose x NCHW f32 -> NHWC fp16, + weight pack, + sums_p zero ----
__global__ __launch_bounds__(256) void prep_kernel(
    const float* __restrict__ x, short* __restrict__ xt,
    const float* __restrict__ w_dcn, const float* __restrict__ w_off,
    const float* __restrict__ w_mask,
    short* __restrict__ wtf_dcn, short* __restrict__ wtf_off,
    float* __restrict__ sums_p)
{
    __shared__ short tl[4096];
    const int t = threadIdx.x;
    const int blk = blockIdx.x;         // 2048 = 8b * 128h * 2wtiles

    if (blk < 216) {                    // folded-in weight pack
        int i = blk * 256 + t;
        if (i < 36864) {                // w_dcn: [(ks*4+nf)*64+lane]*8+e
            int e = i & 7, lane = (i >> 3) & 63, nf = (i >> 9) & 3, ks = i >> 11;
            int tt = ks * 32 + ((lane >> 4) << 3) + e;
            int o = (nf << 4) + (lane & 15);
            int k = tt >> 6, c = tt & 63;
            wtf_dcn[i] = f2h(w_dcn[(o * 64 + c) * 9 + k]);
        } else {                        // w_off/w_mask: [(ks*2+nf)*64+lane]*8+e
            int j = i - 36864;
            int e = j & 7, lane = (j >> 3) & 63, nf = (j >> 9) & 1, ks = j >> 10;
            int tt = ks * 32 + ((lane >> 4) << 3) + e;
            int oc = (nf << 4) + (lane & 15);
            int k = tt >> 6, c = tt & 63;
            float v = 0.f;
            if (oc < 18) v = w_off[(oc * 64 + c) * 9 + k];
            else if (oc < 27) v = w_mask[((oc - 18) * 64 + c) * 9 + k];
            wtf_off[j] = f2h(v);
        }
    } else if (blk == 1000) {           // zero BN partials (16 floats/thread)
#pragma unroll
        for (int i = 0; i < 16; ++i) sums_p[t + 256 * i] = 0.f;
    }

    const int b = blk >> 8, rem = blk & 255, h = rem >> 1, wb = (rem & 1) << 6;
    const int w4 = t & 15, ci = t >> 4;
#pragma unroll
    for (int i = 0; i < 4; ++i) {
        int c = i * 16 + ci;
        f32x4 v = *(const f32x4*)(x + (((b * 64 + c) * 128 + h) * 128) + wb + w4 * 4);
#pragma unroll
        for (int j = 0; j < 4; ++j) {
            int w = w4 * 4 + j;
            tl[w * 64 + (c ^ ((w & 7) << 3))] = f2h(v[j]);
        }
    }
    __syncthreads();
    const int p = t >> 2, q = t & 3;
    f16x8 a = *(const f16x8*)&tl[p * 64 + ((q * 16) ^ ((p & 7) << 3))];
    f16x8 bv = *(const f16x8*)&tl[p * 64 + ((q * 16 + 8) ^ ((p & 7) << 3))];
    short* dst = xt + ((((b << 7) | h) << 7) | (wb + p)) * 64 + q * 16;
    *(f16x8*)dst = a;
    *(f16x8*)(dst + 8) = bv;
}

// ---------------- fused conv: r9-verified structure (single-set prefetch, 1 barrier/k) ----------------
__global__ __launch_bounds__(256, 4) void fused_conv(
    const short* __restrict__ xt,
    const short* __restrict__ wtf_off, const short* __restrict__ wtf_dcn,
    const float* __restrict__ b_off, const float* __restrict__ b_mask,
    const float* __restrict__ b_dcn,
    _Float16* __restrict__ preh, float* __restrict__ sums_p)
{
    __shared__ __align__(16) short alds[2][4096];               // 16 KB double-buffered A-tile
    __shared__ float offy[9][66], offxl[9][66], offmm[9][66];   // padded (conflict-free)
    __shared__ float blkstats[2][64];

    const int tid = threadIdx.x;
    const int bid = blockIdx.x;
    if (tid < 128) blkstats[tid >> 6][tid & 63] = 0.f;

    const int tile = (bid & 7) * 256 + (bid >> 3);  // XCD-bijective, 2048 % 8 == 0
    const int pbase = tile << 6;
    const int b = pbase / HW;
    const int rembase = pbase % HW;                 // 64-px strip (one h row)
    const int hh0 = rembase >> 7;
    const int wb0 = rembase & 127;
    const int p = tid >> 2, q = tid & 3;            // staging role: pixel p, ch-quad q
    const int wp0 = wb0 + p;
    const int lane = tid & 63, wv = tid >> 6;
    const short* xb = xt + ((size_t)b << 20);

    const int ws0 = p * 64 + ((q * 16) ^ ((p & 7) << 3));
    const int ws1 = p * 64 + ((q * 16 + 8) ^ ((p & 7) << 3));

    // ================= Phase A: offset/mask conv (N=32) =================
    const int nfw = wv & 1, mh = wv >> 1;
    f16x8 s0v, s1v;
    auto issueND = [&](int k) {
        int yy = hh0 + (k / 3) - 1;
        int xx = wp0 + (k % 3) - 1;
        bool ok = (yy >= 0) && (yy < HH) && (xx >= 0) && (xx < WW);
        const short* src = xb + (((((yy & 127) << 7) | (xx & 127))) << 6) + q * 16;
        f16x8 z = {};
        s0v = ok ? *(const f16x8*)src : z;
        s1v = ok ? *(const f16x8*)(src + 8) : z;
    };
    auto writeND = [&](int buf) {
        *(f16x8*)&alds[buf][ws0] = s0v;
        *(f16x8*)&alds[buf][ws1] = s1v;
    };

    f32x4 acc2[2];
    acc2[0] = (f32x4){0.f, 0.f, 0.f, 0.f};
    acc2[1] = acc2[0];

    issueND(0);
    writeND(0);
    __syncthreads();
    int s = 0;
#pragma unroll 1
    for (int k = 0; k < 9; ++k) {
        if (k < 8) issueND(k + 1);                  // next-k loads fly under MFMA
        const short* bw = wtf_off + (4 * k + nfw) * 512;
        f16x8 b0 = *(const f16x8*)(bw + lane * 8);
        f16x8 b1 = *(const f16x8*)(bw + 1024 + lane * 8);   // ks=2k+1, same nfw
        __builtin_amdgcn_s_setprio(1);
#pragma unroll
        for (int kh = 0; kh < 2; ++kh) {
            f16x8 bb = kh ? b1 : b0;
#pragma unroll
            for (int i = 0; i < 2; ++i) {
                int px = (mh * 2 + i) * 16 + (lane & 15);
                int sidx = px * 64 + ((kh * 32 + ((lane >> 4) << 3)) ^ ((px & 7) << 3));
                f16x8 af = *(const f16x8*)&alds[s][sidx];
                acc2[i] = mfma_f16(af, bb, acc2[i]);
            }
        }
        __builtin_amdgcn_s_setprio(0);
        if (k < 8) writeND(s ^ 1);                  // other buffer: no hazard with reads
        __syncthreads();
        s ^= 1;
    }
    {   // epilogue A: offsets + sigmoid(mask) -> LDS (wave=(nfw,mh) layout)
        const int rq = lane >> 4;
        const int oc = nfw * 16 + (lane & 15);
#pragma unroll
        for (int i = 0; i < 2; ++i) {
#pragma unroll
            for (int j = 0; j < 4; ++j) {
                int px = (mh * 2 + i) * 16 + rq * 4 + j;
                float v = acc2[i][j];
                if (oc < 18) {
                    v += b_off[oc];
                    if (oc & 1) offxl[oc >> 1][px] = v; else offy[oc >> 1][px] = v;
                } else if (oc < 27) {
                    v += b_mask[oc - 18];
                    offmm[oc - 18][px] = 1.f / (1.f + __expf(-v));
                }
            }
        }
    }
    __syncthreads();

    // ================= Phase B: deformable conv (N=64) =================
    const int nf = wv;                              // wave's 16-col N-fragment
    f32x4 acc[4];
#pragma unroll
    for (int i = 0; i < 4; ++i) acc[i] = (f32x4){0.f, 0.f, 0.f, 0.f};

    f16x8 c00a, c00b, c01a, c01b, c10a, c10b, c11a, c11b;
    _Float16 h00, h01, h10, h11;
    auto bilin = [&](int k) {
        float dyv = offy[k][p], dxv = offxl[k][p], mv = offmm[k][p];
        float py  = (float)(hh0 + (k / 3) - 1) + dyv;
        float pxf = (float)(wp0 + (k % 3) - 1) + dxv;
        float y0f = floorf(py), x0f = floorf(pxf);
        float ly = py - y0f, lx = pxf - x0f;
        int y0 = (int)y0f, x0 = (int)x0f;
        int y1 = y0 + 1, x1 = x0 + 1;
        float fy0 = (y0 >= 0 && y0 < HH) ? 1.f : 0.f;
        float fy1 = (y1 >= 0 && y1 < HH) ? 1.f : 0.f;
        float fx0 = (x0 >= 0 && x0 < WW) ? 1.f : 0.f;
        float fx1 = (x1 >= 0 && x1 < WW) ? 1.f : 0.f;
        int yc0 = min(max(y0, 0), HH - 1), yc1 = min(max(y1, 0), HH - 1);
        int xc0 = min(max(x0, 0), WW - 1), xc1 = min(max(x1, 0), WW - 1);
        h00 = (_Float16)((1.f - ly) * (1.f - lx) * mv * fy0 * fx0);
        h01 = (_Float16)((1.f - ly) * lx * mv * fy0 * fx1);
        h10 = (_Float16)(ly * (1.f - lx) * mv * fy1 * fx0);
        h11 = (_Float16)(ly * lx * mv * fy1 * fx1);
        const short* s00 = xb + (((yc0 << 7) | xc0) << 6) + q * 16;
        const short* s01 = xb + (((yc0 << 7) | xc1) << 6) + q * 16;
        const short* s10 = xb + (((yc1 << 7) | xc0) << 6) + q * 16;
        const short* s11 = xb + (((yc1 << 7) | xc1) << 6) + q * 16;
        c00a = *(const f16x8*)s00; c00b = *(const f16x8*)(s00 + 8);
        c01a = *(const f16x8*)s01; c01b = *(const f16x8*)(s01 + 8);
        c10a = *(const f16x8*)s10; c10b = *(const f16x8*)(s10 + 8);
        c11a = *(const f16x8*)s11; c11b = *(const f16x8*)(s11 + 8);
    };
    auto writeB = [&](int buf) {     // packed-fp16 bilinear interp
        f16x8 va = c00a * h00 + c01a * h01 + c10a * h10 + c11a * h11;
        f16x8 vb = c00b * h00 + c01b * h01 + c10b * h10 + c11b * h11;
        *(f16x8*)&alds[buf][ws0] = va;
        *(f16x8*)&alds[buf][ws1] = vb;
    };

    bilin(0);
    writeB(0);
    __syncthreads();
    s = 0;
#pragma unroll 1
    for (int k = 0; k < 9; ++k) {
        if (k < 8) bilin(k + 1);                    // next-k corner loads under MFMA
        const short* bw = wtf_dcn + (((8 * k) + nf) * 64 + lane) * 8;
        f16x8 b0 = *(const f16x8*)bw;
        f16x8 b1 = *(const f16x8*)(bw + 2048);      // ks=2k+1, same nf
        __builtin_amdgcn_s_setprio(1);
#pragma unroll
        for (int kh = 0; kh < 2; ++kh) {
            f16x8 bb = kh ? b1 : b0;
#pragma unroll
            for (int mb = 0; mb < 4; ++mb) {
                int px = mb * 16 + (lane & 15);
                int sidx = px * 64 + ((kh * 32 + ((lane >> 4) << 3)) ^ ((px & 7) << 3));
                f16x8 af = *(const f16x8*)&alds[s][sidx];
                acc[mb] = mfma_f16(af, bb, acc[mb]);
            }
        }
        __builtin_amdgcn_s_setprio(0);
        if (k < 8) writeB(s ^ 1);
        __syncthreads();
        s ^= 1;
    }

    // epilogue B: o = wv*16 + (lane&15); pixel = mb*16 + rq*4 + j
    {
        const int lr = lane & 15, rq = lane >> 4;
        const int o = nf * 16 + lr;
        const float bo = b_dcn[o];
        _Float16* dstp = preh + (size_t)(b * 64 + o) * HW + rembase;
        float sv = 0.f, s2 = 0.f;
#pragma unroll
        for (int mb = 0; mb < 4; ++mb) {
            f16x4 hv;
#pragma unroll
            for (int j = 0; j < 4; ++j) {
                float v = acc[mb][j] + bo;
                hv[j] = (_Float16)v;
                sv += v; s2 += v * v;
            }
            *(f16x4*)(dstp + mb * 16 + rq * 4) = hv;
        }
        sv += __shfl_xor(sv, 16);  sv += __shfl_xor(sv, 32);
        s2 += __shfl_xor(s2, 16);  s2 += __shfl_xor(s2, 32);
        if (lane < 16) {
            atomicAdd(&blkstats[0][o], sv);
            atomicAdd(&blkstats[1][o], s2);
        }
    }
    __syncthreads();
    if (tid < 64) {
        int slot = bid & 31;
        atomicAdd(&sums_p[slot * 64 + tid], blkstats[0][tid]);           // [slot][ch] coalesced
        atomicAdd(&sums_p[2048 + slot * 64 + tid], blkstats[1][tid]);
    }
}

// ---------------- BN apply + fast Mish: mish(t) = t*(u²+2u)/(u²+2u+2), u=e^t ----------------
__global__ __launch_bounds__(256) void bn_mish(
    const _Float16* __restrict__ preh, const float* __restrict__ sums_p,
    const float* __restrict__ gamma, const float* __restrict__ beta,
    float* __restrict__ out)
{
    int vid = blockIdx.x * 256 + threadIdx.x;       // f16x8 chunk index
    int c = (vid >> 11) & 63;                       // uniform per block
    float sm = 0.f, sq = 0.f;
#pragma unroll
    for (int s = 0; s < 32; ++s) {                  // uniform scalar loads, L2-hot
        sm += sums_p[s * 64 + c];
        sq += sums_p[2048 + s * 64 + c];
    }
    const float invN = 1.f / (float)(BB * HW);
    float mean = sm * invN;
    float rstd = rsqrtf(sq * invN - mean * mean + EPSV);
    float g = gamma[c] * rstd;
    float be = beta[c] - mean * g;
    f16x8 v = ((const f16x8*)preh)[vid];
    float* dst = out + (size_t)vid * 8;
    f32x4 r0, r1;
#pragma unroll
    for (int j = 0; j < 8; ++j) {
        float t = (float)v[j] * g + be;
        float u = __expf(fminf(t, 20.f));
        float w = u * u + 2.f * u;
        float m = t * (w / (w + 2.f));
        if (j < 4) r0[j] = m; else r1[j - 4] = m;
    }
    *(f32x4*)dst = r0;
    *(f32x4*)(dst + 4) = r1;
}

extern "C" void kernel_launch(void* const* d_in, const int* in_sizes, int n_in,
                              void* d_out, int out_size, void* d_ws, size_t ws_size,
                              hipStream_t stream) {
    const float* x      = (const float*)d_in[0];
    const float* w_off  = (const float*)d_in[1];
    const float* b_off  = (const float*)d_in[2];
    const float* w_mask = (const float*)d_in[3];
    const float* b_mask = (const float*)d_in[4];
    const float* w_dcn  = (const float*)d_in[5];
    const float* b_dcn  = (const float*)d_in[6];
    const float* gamma  = (const float*)d_in[7];
    const float* beta   = (const float*)d_in[8];
    float* out = (float*)d_out;

    float* sums_p  = (float*)d_ws;                  // 4096 floats (2 x 32slot x 64ch)
    short* wtf_dcn = (short*)(sums_p + 4096);       // 36864 shorts
    short* wtf_off = wtf_dcn + 36864;               // 18432 shorts
    short* xt      = wtf_off + 18432;               // 8388608 shorts (NHWC fp16)
    _Float16* preh = (_Float16*)(xt + 8388608);     // 8388608 halfs

    prep_kernel<<<2048, 256, 0, stream>>>(x, xt, w_dcn, w_off, w_mask, wtf_dcn, wtf_off, sums_p);
    fused_conv<<<2048, 256, 0, stream>>>(xt, wtf_off, wtf_dcn, b_off, b_mask, b_dcn, preh, sums_p);
    bn_mish<<<4096, 256, 0, stream>>>(preh, sums_p, gamma, beta, out);
}